// Round 1
// baseline (2386.722 us; speedup 1.0000x reference)
//
#include <hip/hip_runtime.h>

typedef __bf16 bf16x8 __attribute__((ext_vector_type(8)));
typedef __bf16 bf16x4 __attribute__((ext_vector_type(4)));
typedef float f32x4 __attribute__((ext_vector_type(4)));

#define EMBED 584
#define HEADS 8
#define HS 73
#define HSP 74   // LDS row stride (even -> 4B-aligned pair reads possible later)
#define CTX 200
#define NBATCH 256
#define MROWS 51200   // NBATCH*CTX
#define NQKV 1752     // 3*EMBED

// ---------------- fp32 -> bf16 convert (x), 4 elems/thread ----------------
__global__ __launch_bounds__(256) void cvt_x(const float4* __restrict__ in,
                                             __bf16* __restrict__ out) {
  int i = blockIdx.x * 256 + threadIdx.x;
  float4 f = in[i];
  bf16x4 o;
  o[0] = (__bf16)f.x; o[1] = (__bf16)f.y; o[2] = (__bf16)f.z; o[3] = (__bf16)f.w;
  *(bf16x4*)(out + (size_t)i * 4) = o;
}

// ------------- pack Wq|Wk|Wv|Wo -> bf16 [2336, 584] row-major -------------
__global__ __launch_bounds__(256) void pack_w(const float* __restrict__ Wq,
                                              const float* __restrict__ Wk,
                                              const float* __restrict__ Wv,
                                              const float* __restrict__ Wo,
                                              __bf16* __restrict__ out) {
  int i = blockIdx.x * 256 + threadIdx.x;
  const int G = EMBED * EMBED;  // 341056
  float val;
  if (i < G)            val = Wq[i];
  else if (i < 2 * G)   val = Wk[i - G];
  else if (i < 3 * G)   val = Wv[i - 2 * G];
  else                  val = Wo[i - 3 * G];
  out[i] = (__bf16)val;
}

// ---------------- QKV projection GEMM: C = A[M,K] * B[N,K]^T --------------
// 128x128 block tile, BK=32, 4 waves (2x2), each wave 4x4 of 16x16x32 MFMA.
// Epilogue scatters to q/k/v bf16 [B*H, T, HS].
__global__ __launch_bounds__(256) void gemm_qkv(const __bf16* __restrict__ A,
                                                const __bf16* __restrict__ Bm,
                                                __bf16* __restrict__ Q,
                                                __bf16* __restrict__ Ko,
                                                __bf16* __restrict__ V) {
  constexpr int N = NQKV, K = EMBED;
  __shared__ __bf16 As[128 * 32];
  __shared__ __bf16 Bs[128 * 32];
  int tid = threadIdx.x;
  int bm = blockIdx.x, bn = blockIdx.y;
  int wid = tid >> 6, lane = tid & 63;
  int wm = (wid & 1) * 64, wn = (wid >> 1) * 64;
  int lr = lane & 15, lq = lane >> 4;
  f32x4 acc[4][4] = {};
  const int KT = (K + 31) / 32;  // 19
  for (int kt = 0; kt < KT; ++kt) {
    int k0 = kt * 32;
#pragma unroll
    for (int it = 0; it < 2; ++it) {
      int vv = tid + it * 256;           // 0..511
      int row = vv >> 2;
      int kc = (vv & 3) * 8;
      int kg = k0 + kc;
      bf16x8 av = {};
      if (kg < K) av = *(const bf16x8*)(A + (size_t)(bm * 128 + row) * K + kg);
      *(bf16x8*)&As[row * 32 + kc] = av;
      int ng = bn * 128 + row;
      bf16x8 bv = {};
      if (kg < K && ng < N) bv = *(const bf16x8*)(Bm + (size_t)ng * K + kg);
      *(bf16x8*)&Bs[row * 32 + kc] = bv;
    }
    __syncthreads();
    bf16x8 af[4], bfr[4];
#pragma unroll
    for (int i = 0; i < 4; ++i)
      af[i] = *(const bf16x8*)&As[(wm + i * 16 + lr) * 32 + lq * 8];
#pragma unroll
    for (int j = 0; j < 4; ++j)
      bfr[j] = *(const bf16x8*)&Bs[(wn + j * 16 + lr) * 32 + lq * 8];
#pragma unroll
    for (int i = 0; i < 4; ++i)
#pragma unroll
      for (int j = 0; j < 4; ++j)
        acc[i][j] = __builtin_amdgcn_mfma_f32_16x16x32_bf16(af[i], bfr[j], acc[i][j], 0, 0, 0);
    __syncthreads();
  }
  // epilogue: C row m=(lane>>4)*4+r, col n=lane&15; scatter to [B*H, T, HS]
#pragma unroll
  for (int i = 0; i < 4; ++i) {
    int m = bm * 128 + wm + i * 16 + lq * 4;
#pragma unroll
    for (int j = 0; j < 4; ++j) {
      int n = bn * 128 + wn + j * 16 + lr;
      if (n < N) {
        int which = n / EMBED;
        int rem = n - which * EMBED;
        int hh = rem / HS;
        int f = rem - hh * HS;
        __bf16* dst = which == 0 ? Q : (which == 1 ? Ko : V);
#pragma unroll
        for (int r = 0; r < 4; ++r) {
          int mm = m + r;
          int bb = mm / CTX;
          int tt = mm - bb * CTX;
          dst[((size_t)((bb * HEADS + hh) * CTX + tt)) * HS + f] = (__bf16)acc[i][j][r];
        }
      }
    }
  }
}

// ---------------- attention: one block per (b,h) --------------------------
__global__ __launch_bounds__(256) void attn_kernel(const __bf16* __restrict__ q,
                                                   const __bf16* __restrict__ k,
                                                   const __bf16* __restrict__ v,
                                                   __bf16* __restrict__ o) {
  __shared__ __bf16 Ks[CTX * HSP];   // 29.6 KB
  __shared__ __bf16 Vs[CTX * HSP];   // 29.6 KB
  __shared__ float qs[4][80];        // per-wave current query
  __shared__ float ps[4][CTX];       // per-wave probabilities
  int tid = threadIdx.x;
  int bh = blockIdx.x;
  int b = bh >> 3, h = bh & 7;
  const __bf16* qg = q + (size_t)bh * (CTX * HS);
  const __bf16* kg = k + (size_t)bh * (CTX * HS);
  const __bf16* vg = v + (size_t)bh * (CTX * HS);
  for (int i = tid; i < CTX * HS; i += 256) {
    int s = i / HS;
    int e = i - s * HS;
    Ks[s * HSP + e] = kg[i];
    Vs[s * HSP + e] = vg[i];
  }
  __syncthreads();
  int wid = tid >> 6, lane = tid & 63;
  const float scale = 0.04138029443264672f;  // 584^-0.5
  for (int qi = 0; qi < CTX / 4; ++qi) {
    int t = qi * 4 + wid;
    // stage q_t into per-wave LDS (same-wave RAW; in-order LDS + compiler waitcnt)
    qs[wid][lane] = (float)qg[t * HS + lane];
    if (lane < HS - 64) qs[wid][64 + lane] = (float)qg[t * HS + 64 + lane];
    float sc[4];
#pragma unroll
    for (int c = 0; c < 4; ++c) {
      int key = lane + c * 64;
      sc[c] = -1e30f;
      if (key <= t) {
        float d = 0.f;
        for (int e = 0; e < HS; ++e) d += qs[wid][e] * (float)Ks[key * HSP + e];
        sc[c] = d * scale;
      }
    }
    float m = fmaxf(fmaxf(sc[0], sc[1]), fmaxf(sc[2], sc[3]));
#pragma unroll
    for (int off = 32; off; off >>= 1) m = fmaxf(m, __shfl_xor(m, off, 64));
    float p[4];
    float sum = 0.f;
#pragma unroll
    for (int c = 0; c < 4; ++c) { p[c] = __expf(sc[c] - m); sum += p[c]; }
#pragma unroll
    for (int off = 32; off; off >>= 1) sum += __shfl_xor(sum, off, 64);
    float inv = 1.0f / sum;
#pragma unroll
    for (int c = 0; c < 4; ++c) {
      int key = lane + c * 64;
      if (key < CTX) ps[wid][key] = p[c] * inv;
    }
    float o0 = 0.f, o1 = 0.f;
    for (int s = 0; s <= t; ++s) {
      float w = ps[wid][s];
      o0 += w * (float)Vs[s * HSP + lane];
      if (lane < HS - 64) o1 += w * (float)Vs[s * HSP + 64 + lane];
    }
    size_t ob = ((size_t)(b * CTX + t)) * EMBED + h * HS;
    o[ob + lane] = (__bf16)o0;
    if (lane < HS - 64) o[ob + 64 + lane] = (__bf16)o1;
  }
}

// ---------------- output projection GEMM + bias, fp32 out -----------------
__global__ __launch_bounds__(256) void gemm_out(const __bf16* __restrict__ A,
                                                const __bf16* __restrict__ Bm,
                                                const float* __restrict__ bias,
                                                float* __restrict__ C) {
  constexpr int N = EMBED, K = EMBED;
  __shared__ __bf16 As[128 * 32];
  __shared__ __bf16 Bs[128 * 32];
  int tid = threadIdx.x;
  int bm = blockIdx.x, bn = blockIdx.y;
  int wid = tid >> 6, lane = tid & 63;
  int wm = (wid & 1) * 64, wn = (wid >> 1) * 64;
  int lr = lane & 15, lq = lane >> 4;
  f32x4 acc[4][4] = {};
  const int KT = (K + 31) / 32;
  for (int kt = 0; kt < KT; ++kt) {
    int k0 = kt * 32;
#pragma unroll
    for (int it = 0; it < 2; ++it) {
      int vv = tid + it * 256;
      int row = vv >> 2;
      int kc = (vv & 3) * 8;
      int kg = k0 + kc;
      bf16x8 av = {};
      if (kg < K) av = *(const bf16x8*)(A + (size_t)(bm * 128 + row) * K + kg);
      *(bf16x8*)&As[row * 32 + kc] = av;
      int ng = bn * 128 + row;
      bf16x8 bv = {};
      if (kg < K && ng < N) bv = *(const bf16x8*)(Bm + (size_t)ng * K + kg);
      *(bf16x8*)&Bs[row * 32 + kc] = bv;
    }
    __syncthreads();
    bf16x8 af[4], bfr[4];
#pragma unroll
    for (int i = 0; i < 4; ++i)
      af[i] = *(const bf16x8*)&As[(wm + i * 16 + lr) * 32 + lq * 8];
#pragma unroll
    for (int j = 0; j < 4; ++j)
      bfr[j] = *(const bf16x8*)&Bs[(wn + j * 16 + lr) * 32 + lq * 8];
#pragma unroll
    for (int i = 0; i < 4; ++i)
#pragma unroll
      for (int j = 0; j < 4; ++j)
        acc[i][j] = __builtin_amdgcn_mfma_f32_16x16x32_bf16(af[i], bfr[j], acc[i][j], 0, 0, 0);
    __syncthreads();
  }
#pragma unroll
  for (int i = 0; i < 4; ++i) {
    int m = bm * 128 + wm + i * 16 + lq * 4;
#pragma unroll
    for (int j = 0; j < 4; ++j) {
      int n = bn * 128 + wn + j * 16 + lr;
      if (n < N) {
        float bval = bias[n];
#pragma unroll
        for (int r = 0; r < 4; ++r)
          C[(size_t)(m + r) * N + n] = acc[i][j][r] + bval;
      }
    }
  }
}

extern "C" void kernel_launch(void* const* d_in, const int* in_sizes, int n_in,
                              void* d_out, int out_size, void* d_ws, size_t ws_size,
                              hipStream_t stream) {
  const float* x  = (const float*)d_in[0];
  const float* Wq = (const float*)d_in[1];
  const float* Wk = (const float*)d_in[2];
  const float* Wv = (const float*)d_in[3];
  const float* Wo = (const float*)d_in[4];
  const float* bo = (const float*)d_in[5];
  float* out = (float*)d_out;

  // ws layout (bf16 elements):
  //  xb   [51200*584]      = 29,900,800
  //  wcat [2336*584]       =  1,364,224   (Wq|Wk|Wv rows 0..1751, Wo rows 1752..2335)
  //  qb, kb, vb [2048*200*73] each = 29,900,800
  //  ab   [51200*584]      = 29,900,800   (attention out, head-concat layout)
  __bf16* xb   = (__bf16*)d_ws;
  __bf16* wcat = xb + 29900800ULL;
  __bf16* qb   = wcat + 1364224ULL;
  __bf16* kb   = qb + 29900800ULL;
  __bf16* vb   = kb + 29900800ULL;
  __bf16* ab   = vb + 29900800ULL;

  // 1) x -> bf16 : 29,900,800/4 = 7,475,200 threads = 29200 blocks
  cvt_x<<<29200, 256, 0, stream>>>((const float4*)x, xb);
  // 2) pack weights: 1,364,224 / 256 = 5329 blocks
  pack_w<<<5329, 256, 0, stream>>>(Wq, Wk, Wv, Wo, wcat);
  // 3) QKV projection: M=51200 (400 tiles) x N=1752 (14 tiles)
  gemm_qkv<<<dim3(400, 14), 256, 0, stream>>>(xb, wcat, qb, kb, vb);
  // 4) attention: one block per (b,h)
  attn_kernel<<<2048, 256, 0, stream>>>(qb, kb, vb, ab);
  // 5) output projection: N=584 (5 tiles), Wo rows start at 1752
  gemm_out<<<dim3(400, 5), 256, 0, stream>>>(ab, wcat + 1752ULL * EMBED, bo, out);
}

// Round 3
// 877.412 us; speedup vs baseline: 2.7202x; 2.7202x over previous
//
#include <hip/hip_runtime.h>

typedef __bf16 bf16x8 __attribute__((ext_vector_type(8)));
typedef __bf16 bf16x4 __attribute__((ext_vector_type(4)));
typedef float f32x4 __attribute__((ext_vector_type(4)));

#define EMBED 584
#define HEADS 8
#define HS 73
#define HSQ 80    // padded head size in q/k storage (16B-aligned rows)
#define CTX 200
#define NBATCH 256
#define MROWS 51200   // NBATCH*CTX
#define NQKV 1752     // 3*EMBED

// attention LDS geometry (halfword strides, all rows 16B-aligned)
#define CH 112      // keys per chunk (2 chunks cover 224 >= 200)
#define KSS 104     // Ks stride: 96 cols used + 8 pad (208 B rows)
#define VTS 136     // Vt stride: 128 cols used + 8 pad (272 B rows)
#define PSS 136     // Ps stride

// ---------------- fp32 -> bf16 convert (x), 4 elems/thread ----------------
__global__ __launch_bounds__(256) void cvt_x(const float4* __restrict__ in,
                                             __bf16* __restrict__ out) {
  int i = blockIdx.x * 256 + threadIdx.x;
  float4 f = in[i];
  bf16x4 o;
  o[0] = (__bf16)f.x; o[1] = (__bf16)f.y; o[2] = (__bf16)f.z; o[3] = (__bf16)f.w;
  *(bf16x4*)(out + (size_t)i * 4) = o;
}

// ------------- pack Wq|Wk|Wv|Wo -> bf16 [2336, 584] row-major -------------
__global__ __launch_bounds__(256) void pack_w(const float* __restrict__ Wq,
                                              const float* __restrict__ Wk,
                                              const float* __restrict__ Wv,
                                              const float* __restrict__ Wo,
                                              __bf16* __restrict__ out) {
  int i = blockIdx.x * 256 + threadIdx.x;
  const int G = EMBED * EMBED;  // 341056
  float val;
  if (i < G)            val = Wq[i];
  else if (i < 2 * G)   val = Wk[i - G];
  else if (i < 3 * G)   val = Wv[i - 2 * G];
  else                  val = Wo[i - 3 * G];
  out[i] = (__bf16)val;
}

// ---------------- QKV projection GEMM: C = A[M,K] * B[N,K]^T --------------
// Epilogue: Q,K -> [bh][t][HSQ] (f<73); V -> [bh][f][CTX] (transposed).
__global__ __launch_bounds__(256) void gemm_qkv(const __bf16* __restrict__ A,
                                                const __bf16* __restrict__ Bm,
                                                __bf16* __restrict__ Q,
                                                __bf16* __restrict__ Ko,
                                                __bf16* __restrict__ V) {
  constexpr int N = NQKV, K = EMBED;
  __shared__ __bf16 As[128 * 32];
  __shared__ __bf16 Bs[128 * 32];
  int tid = threadIdx.x;
  int bm = blockIdx.x, bn = blockIdx.y;
  int wid = tid >> 6, lane = tid & 63;
  int wm = (wid & 1) * 64, wn = (wid >> 1) * 64;
  int lr = lane & 15, lq = lane >> 4;
  f32x4 acc[4][4] = {};
  const int KT = (K + 31) / 32;  // 19
  for (int kt = 0; kt < KT; ++kt) {
    int k0 = kt * 32;
#pragma unroll
    for (int it = 0; it < 2; ++it) {
      int vv = tid + it * 256;           // 0..511
      int row = vv >> 2;
      int kc = (vv & 3) * 8;
      int kg = k0 + kc;
      bf16x8 av = {};
      if (kg < K) av = *(const bf16x8*)(A + (size_t)(bm * 128 + row) * K + kg);
      *(bf16x8*)&As[row * 32 + kc] = av;
      int ng = bn * 128 + row;
      bf16x8 bv = {};
      if (kg < K && ng < N) bv = *(const bf16x8*)(Bm + (size_t)ng * K + kg);
      *(bf16x8*)&Bs[row * 32 + kc] = bv;
    }
    __syncthreads();
    bf16x8 af[4], bfr[4];
#pragma unroll
    for (int i = 0; i < 4; ++i)
      af[i] = *(const bf16x8*)&As[(wm + i * 16 + lr) * 32 + lq * 8];
#pragma unroll
    for (int j = 0; j < 4; ++j)
      bfr[j] = *(const bf16x8*)&Bs[(wn + j * 16 + lr) * 32 + lq * 8];
#pragma unroll
    for (int i = 0; i < 4; ++i)
#pragma unroll
      for (int j = 0; j < 4; ++j)
        acc[i][j] = __builtin_amdgcn_mfma_f32_16x16x32_bf16(af[i], bfr[j], acc[i][j], 0, 0, 0);
    __syncthreads();
  }
  // epilogue: C row m=(lane>>4)*4+r, col n=lane&15
#pragma unroll
  for (int i = 0; i < 4; ++i) {
    int m = bm * 128 + wm + i * 16 + lq * 4;
#pragma unroll
    for (int j = 0; j < 4; ++j) {
      int n = bn * 128 + wn + j * 16 + lr;
      if (n < N) {
        int which = n / EMBED;
        int rem = n - which * EMBED;
        int hh = rem / HS;
        int f = rem - hh * HS;
#pragma unroll
        for (int r = 0; r < 4; ++r) {
          int mm = m + r;
          int bb = mm / CTX;
          int tt = mm - bb * CTX;
          int bh = bb * HEADS + hh;
          __bf16 val = (__bf16)acc[i][j][r];
          if (which == 0)
            Q[((size_t)bh * CTX + tt) * HSQ + f] = val;
          else if (which == 1)
            Ko[((size_t)bh * CTX + tt) * HSQ + f] = val;
          else
            V[((size_t)bh * HSQ + f) * CTX + tt] = val;
        }
      }
    }
  }
}

// ---------------- MFMA flash attention: one block per (b,h) ---------------
// Q,K: [bh][t][80] bf16 ; V: [bh][f][200] bf16 (transposed). Out: [B,T,584].
__global__ __launch_bounds__(256) void attn_kernel(const __bf16* __restrict__ q,
                                                   const __bf16* __restrict__ k,
                                                   const __bf16* __restrict__ v,
                                                   __bf16* __restrict__ o) {
  // LDS: Ks[112][104] + Vt[80][136] + Ps[4][16][136] = 62464 B
  __shared__ __align__(16) __bf16 lds[31232];
  __bf16* Ks = lds;                 // 11648 hw
  __bf16* Vt = lds + 11648;         // 10880 hw
  __bf16* Ps = lds + 22528;         //  8704 hw (4 waves x 2176)

  int tid = threadIdx.x;
  int bh = blockIdx.x;
  int b = bh >> 3, h = bh & 7;
  const __bf16* qg = q + (size_t)bh * (CTX * HSQ);
  const __bf16* kg = k + (size_t)bh * (CTX * HSQ);
  const __bf16* vg = v + (size_t)bh * (HSQ * CTX);

  // zero all LDS once (pad cols MUST be 0.0, not junk: 0*NaN=NaN)
  {
    f32x4* p = (f32x4*)lds;
    for (int i = tid; i < 3904; i += 256) p[i] = f32x4{0.f, 0.f, 0.f, 0.f};
  }
  __syncthreads();

  int wid = tid >> 6, lane = tid & 63;
  int lr = lane & 15, g = lane >> 4;
  __bf16* Pw = Ps + wid * (16 * PSS);
  const int nstr = (wid == 0) ? 4 : 3;   // strips: wid, wid+4, wid+8, (12)
  const float scale = 0.04138029443264672f;  // 584^-0.5

  float ml[4][4], ll[4][4];
  f32x4 ov[4][5];
#pragma unroll
  for (int i = 0; i < 4; ++i)
#pragma unroll
    for (int r = 0; r < 4; ++r) { ml[i][r] = -1e30f; ll[i][r] = 0.f; }
#pragma unroll
  for (int i = 0; i < 4; ++i)
#pragma unroll
    for (int nt = 0; nt < 5; ++nt) ov[i][nt] = f32x4{0.f, 0.f, 0.f, 0.f};

  for (int c = 0; c < 2; ++c) {
    int key0 = c * CH;
    // ---- stage Ks [s][f] from K rows (coalesced: contiguous global) ----
    for (int idx = tid; idx < CH * 10; idx += 256) {
      int s = idx / 10, slot = idx % 10;
      int key = key0 + s;
      if (key < CTX)
        *(bf16x8*)&Ks[s * KSS + slot * 8] =
            *(const bf16x8*)&kg[(size_t)key * HSQ + slot * 8];
    }
    // ---- stage Vt [f][s] from transposed V rows ----
    for (int idx = tid; idx < HSQ * 14; idx += 256) {
      int f = idx / 14, slot = idx % 14;
      int s0 = slot * 8;
      bf16x8 vv;
      if (key0 + s0 + 7 < CTX) {
        vv = *(const bf16x8*)&vg[(size_t)f * CTX + key0 + s0];
      } else {
#pragma unroll
        for (int j = 0; j < 8; ++j)
          vv[j] = (key0 + s0 + j < CTX) ? vg[(size_t)f * CTX + key0 + s0 + j]
                                        : (__bf16)0.f;
      }
      *(bf16x8*)&Vt[f * VTS + s0] = vv;
    }
    __syncthreads();

#pragma unroll
    for (int i = 0; i < 4; ++i) {
      if (i >= nstr) break;
      int strip = wid + 4 * i;
      int row0 = strip * 16;
      // Q A-fragments: A[m=lr][kf=g*8+j + kc*32]
      bf16x8 qf[3];
      qf[0] = *(const bf16x8*)&qg[(size_t)(row0 + lr) * HSQ + g * 8];
      qf[1] = *(const bf16x8*)&qg[(size_t)(row0 + lr) * HSQ + 32 + g * 8];
      if (g < 2)
        qf[2] = *(const bf16x8*)&qg[(size_t)(row0 + lr) * HSQ + 64 + g * 8];
      else
        qf[2] = bf16x8{};
      // ---- S = Q K^T over this chunk ----
      float sc[7][4];
#pragma unroll
      for (int nt = 0; nt < 7; ++nt) {
        f32x4 acc = {};
#pragma unroll
        for (int kc = 0; kc < 3; ++kc) {
          bf16x8 kf = *(const bf16x8*)&Ks[(nt * 16 + lr) * KSS + kc * 32 + g * 8];
          acc = __builtin_amdgcn_mfma_f32_16x16x32_bf16(qf[kc], kf, acc, 0, 0, 0);
        }
        int kcol = key0 + nt * 16 + lr;
#pragma unroll
        for (int r = 0; r < 4; ++r) {
          int qrow = row0 + g * 4 + r;
          sc[nt][r] = (kcol <= qrow && kcol < CTX) ? acc[r] * scale : -1e30f;
        }
      }
      // ---- online softmax (row state; reduce across the 16 lr lanes) ----
      float mc[4];
#pragma unroll
      for (int r = 0; r < 4; ++r) {
        float m = sc[0][r];
#pragma unroll
        for (int nt = 1; nt < 7; ++nt) m = fmaxf(m, sc[nt][r]);
        mc[r] = m;
      }
#pragma unroll
      for (int off = 8; off; off >>= 1)
#pragma unroll
        for (int r = 0; r < 4; ++r)
          mc[r] = fmaxf(mc[r], __shfl_xor(mc[r], off, 64));
      float alpha[4], rs[4];
#pragma unroll
      for (int r = 0; r < 4; ++r) {
        float mnew = fmaxf(ml[i][r], mc[r]);
        alpha[r] = __expf(ml[i][r] - mnew);
        ml[i][r] = mnew;
        float s = 0.f;
#pragma unroll
        for (int nt = 0; nt < 7; ++nt) {
          sc[nt][r] = __expf(sc[nt][r] - mnew);
          s += sc[nt][r];
        }
        rs[r] = s;
      }
#pragma unroll
      for (int off = 8; off; off >>= 1)
#pragma unroll
        for (int r = 0; r < 4; ++r) rs[r] += __shfl_xor(rs[r], off, 64);
#pragma unroll
      for (int r = 0; r < 4; ++r) ll[i][r] = ll[i][r] * alpha[r] + rs[r];
#pragma unroll
      for (int nt = 0; nt < 5; ++nt)
#pragma unroll
        for (int r = 0; r < 4; ++r) ov[i][nt][r] *= alpha[r];
      // ---- P -> per-wave LDS (C-layout -> A-layout round trip) ----
#pragma unroll
      for (int nt = 0; nt < 7; ++nt)
#pragma unroll
        for (int r = 0; r < 4; ++r)
          Pw[(g * 4 + r) * PSS + nt * 16 + lr] = (__bf16)sc[nt][r];
      // ---- O += P V ----
#pragma unroll
      for (int kc = 0; kc < 4; ++kc) {
        bf16x8 pf = *(const bf16x8*)&Pw[lr * PSS + kc * 32 + g * 8];
#pragma unroll
        for (int nt = 0; nt < 5; ++nt) {
          bf16x8 vf = *(const bf16x8*)&Vt[(nt * 16 + lr) * VTS + kc * 32 + g * 8];
          ov[i][nt] = __builtin_amdgcn_mfma_f32_16x16x32_bf16(pf, vf, ov[i][nt], 0, 0, 0);
        }
      }
    }
    __syncthreads();
  }
  // ---- finalize: O / l, store to [B,T,584] head-concat ----
#pragma unroll
  for (int i = 0; i < 4; ++i) {
    if (i >= nstr) break;
    int strip = wid + 4 * i;
    float inv[4];
#pragma unroll
    for (int r = 0; r < 4; ++r) inv[r] = 1.0f / ll[i][r];
#pragma unroll
    for (int nt = 0; nt < 5; ++nt) {
      int f = nt * 16 + lr;
      if (f < HS) {
#pragma unroll
        for (int r = 0; r < 4; ++r) {
          int t = strip * 16 + g * 4 + r;
          if (t < CTX)
            o[((size_t)(b * CTX + t)) * EMBED + h * HS + f] =
                (__bf16)(ov[i][nt][r] * inv[r]);
        }
      }
    }
  }
}

// ---------------- output projection GEMM + bias, fp32 out -----------------
__global__ __launch_bounds__(256) void gemm_out(const __bf16* __restrict__ A,
                                                const __bf16* __restrict__ Bm,
                                                const float* __restrict__ bias,
                                                float* __restrict__ C) {
  constexpr int N = EMBED, K = EMBED;
  __shared__ __bf16 As[128 * 32];
  __shared__ __bf16 Bs[128 * 32];
  int tid = threadIdx.x;
  int bm = blockIdx.x, bn = blockIdx.y;
  int wid = tid >> 6, lane = tid & 63;
  int wm = (wid & 1) * 64, wn = (wid >> 1) * 64;
  int lr = lane & 15, lq = lane >> 4;
  f32x4 acc[4][4] = {};
  const int KT = (K + 31) / 32;
  for (int kt = 0; kt < KT; ++kt) {
    int k0 = kt * 32;
#pragma unroll
    for (int it = 0; it < 2; ++it) {
      int vv = tid + it * 256;
      int row = vv >> 2;
      int kc = (vv & 3) * 8;
      int kg = k0 + kc;
      bf16x8 av = {};
      if (kg < K) av = *(const bf16x8*)(A + (size_t)(bm * 128 + row) * K + kg);
      *(bf16x8*)&As[row * 32 + kc] = av;
      int ng = bn * 128 + row;
      bf16x8 bv = {};
      if (kg < K && ng < N) bv = *(const bf16x8*)(Bm + (size_t)ng * K + kg);
      *(bf16x8*)&Bs[row * 32 + kc] = bv;
    }
    __syncthreads();
    bf16x8 af[4], bfr[4];
#pragma unroll
    for (int i = 0; i < 4; ++i)
      af[i] = *(const bf16x8*)&As[(wm + i * 16 + lr) * 32 + lq * 8];
#pragma unroll
    for (int j = 0; j < 4; ++j)
      bfr[j] = *(const bf16x8*)&Bs[(wn + j * 16 + lr) * 32 + lq * 8];
#pragma unroll
    for (int i = 0; i < 4; ++i)
#pragma unroll
      for (int j = 0; j < 4; ++j)
        acc[i][j] = __builtin_amdgcn_mfma_f32_16x16x32_bf16(af[i], bfr[j], acc[i][j], 0, 0, 0);
    __syncthreads();
  }
#pragma unroll
  for (int i = 0; i < 4; ++i) {
    int m = bm * 128 + wm + i * 16 + lq * 4;
#pragma unroll
    for (int j = 0; j < 4; ++j) {
      int n = bn * 128 + wn + j * 16 + lr;
      if (n < N) {
        float bval = bias[n];
#pragma unroll
        for (int r = 0; r < 4; ++r)
          C[(size_t)(m + r) * N + n] = acc[i][j][r] + bval;
      }
    }
  }
}

extern "C" void kernel_launch(void* const* d_in, const int* in_sizes, int n_in,
                              void* d_out, int out_size, void* d_ws, size_t ws_size,
                              hipStream_t stream) {
  const float* x  = (const float*)d_in[0];
  const float* Wq = (const float*)d_in[1];
  const float* Wk = (const float*)d_in[2];
  const float* Wv = (const float*)d_in[3];
  const float* Wo = (const float*)d_in[4];
  const float* bo = (const float*)d_in[5];
  float* out = (float*)d_out;

  // ws layout (bf16 elems), total 129,569,024 elems = 259 MB:
  //  xb   [51200*584]  = 29,900,800  (also reused as ab after gemm_qkv)
  //  wcat [2336*584]   =  1,364,224
  //  qb   [2048*200*80]= 32,768,000
  //  kb   [2048*200*80]= 32,768,000
  //  vb   [2048*80*200]= 32,768,000  (transposed: [bh][f][t])
  __bf16* xb   = (__bf16*)d_ws;
  __bf16* wcat = xb + 29900800ULL;
  __bf16* qb   = wcat + 1364224ULL;
  __bf16* kb   = qb + 32768000ULL;
  __bf16* vb   = kb + 32768000ULL;
  __bf16* ab   = xb;  // alias: xb dead after gemm_qkv

  cvt_x<<<29200, 256, 0, stream>>>((const float4*)x, xb);
  pack_w<<<5329, 256, 0, stream>>>(Wq, Wk, Wv, Wo, wcat);
  gemm_qkv<<<dim3(400, 14), 256, 0, stream>>>(xb, wcat, qb, kb, vb);
  attn_kernel<<<2048, 256, 0, stream>>>(qb, kb, vb, ab);
  gemm_out<<<dim3(400, 5), 256, 0, stream>>>(ab, wcat + 1752ULL * EMBED, bo, out);
}

// Round 4
// 742.041 us; speedup vs baseline: 3.2164x; 1.1824x over previous
//
#include <hip/hip_runtime.h>

typedef __bf16 bf16x8 __attribute__((ext_vector_type(8)));
typedef __bf16 bf16x4 __attribute__((ext_vector_type(4)));
typedef float f32x4 __attribute__((ext_vector_type(4)));

#define EMBED 584
#define KP 608      // K padded to 19*32 (zero-filled cols 584..607)
#define HEADS 8
#define HS 73
#define HSQ 80      // padded head size in q/k storage (16B-aligned rows)
#define CTX 200
#define NBATCH 256
#define MROWS 51200 // NBATCH*CTX
#define NQKV 1752   // 3*EMBED

// attention LDS geometry (halfword strides, all rows 16B-aligned)
#define CH 112      // keys per chunk (2 chunks cover 224 >= 200)
#define KSS 104     // Ks stride: 96 cols used + 8 pad (208 B rows)
#define VTS 136     // Vt stride: 128 cols used + 8 pad (272 B rows)
#define PSS 136     // Ps stride

// async global->LDS 16B copy: LDS dest is wave-uniform base + lane*16
__device__ __forceinline__ void gld_lds16(__bf16* lds, const __bf16* g) {
  __builtin_amdgcn_global_load_lds(
      (const __attribute__((address_space(1))) void*)g,
      (__attribute__((address_space(3))) void*)lds, 16, 0, 0);
}

// ---- fp32 -> bf16 convert x into padded [51200][608], 8 elems/thread ----
__global__ __launch_bounds__(256) void cvt_x(const float* __restrict__ x,
                                             __bf16* __restrict__ out) {
  int i = blockIdx.x * 256 + threadIdx.x;   // 15200*256 = 3,891,200 exact
  int r = i / 76, slot = i - r * 76;
  int col = slot * 8;
  bf16x8 o8 = {};
  if (col < EMBED) {
    const float4* s4 = (const float4*)(x + (size_t)r * EMBED + col);
    float4 f0 = s4[0], f1 = s4[1];
    o8[0] = (__bf16)f0.x; o8[1] = (__bf16)f0.y; o8[2] = (__bf16)f0.z; o8[3] = (__bf16)f0.w;
    o8[4] = (__bf16)f1.x; o8[5] = (__bf16)f1.y; o8[6] = (__bf16)f1.z; o8[7] = (__bf16)f1.w;
  }
  *(bf16x8*)(out + (size_t)r * KP + col) = o8;
}

// ---- pack Wq|Wk|Wv|Wo -> bf16 [2336][608] (zero pad cols) ----
__global__ __launch_bounds__(256) void pack_w(const float* __restrict__ Wq,
                                              const float* __restrict__ Wk,
                                              const float* __restrict__ Wv,
                                              const float* __restrict__ Wo,
                                              __bf16* __restrict__ out) {
  int i = blockIdx.x * 256 + threadIdx.x;
  if (i >= 2336 * 76) return;
  int r = i / 76, slot = i - r * 76;
  int col = slot * 8;
  bf16x8 o8 = {};
  if (col < EMBED) {
    const float* src = r < 584  ? Wq + (size_t)r * EMBED
                     : r < 1168 ? Wk + (size_t)(r - 584) * EMBED
                     : r < 1752 ? Wv + (size_t)(r - 1168) * EMBED
                                : Wo + (size_t)(r - 1752) * EMBED;
    const float4* s4 = (const float4*)(src + col);
    float4 f0 = s4[0], f1 = s4[1];
    o8[0] = (__bf16)f0.x; o8[1] = (__bf16)f0.y; o8[2] = (__bf16)f0.z; o8[3] = (__bf16)f0.w;
    o8[4] = (__bf16)f1.x; o8[5] = (__bf16)f1.y; o8[6] = (__bf16)f1.z; o8[7] = (__bf16)f1.w;
  }
  *(bf16x8*)(out + (size_t)r * KP + col) = o8;
}

// ---------------- QKV projection GEMM: C = A[M,KP] * B[N,KP]^T ------------
// async LDS staging (m97 style); epilogue: Q,K -> [bh][t][80]; V -> [bh][f][200].
__global__ __launch_bounds__(256) void gemm_qkv(const __bf16* __restrict__ A,
                                                const __bf16* __restrict__ Bm,
                                                __bf16* __restrict__ Q,
                                                __bf16* __restrict__ Ko,
                                                __bf16* __restrict__ V) {
  constexpr int N = NQKV;
  __shared__ __bf16 As[128 * 32];
  __shared__ __bf16 Bs[128 * 32];
  int tid = threadIdx.x;
  int bn = blockIdx.x, bm = blockIdx.y;   // bn fast-varying: A-tile L2 reuse
  int wid = tid >> 6, lane = tid & 63;
  int wm = (wid & 1) * 64, wn = (wid >> 1) * 64;
  int lr = lane & 15, lq = lane >> 4;
  // staging addresses: wave wid covers rows [32*wid, 32*wid+32)
  const __bf16* aB = A  + (size_t)(bm * 128 + wid * 32 + (lane >> 2)) * KP + (lane & 3) * 8;
  const __bf16* bB = Bm + (size_t)(bn * 128 + wid * 32 + (lane >> 2)) * KP + (lane & 3) * 8;
  __bf16* asD = As + wid * 1024;
  __bf16* bsD = Bs + wid * 1024;
  f32x4 acc[4][4] = {};
  for (int kt = 0; kt < 19; ++kt) {
    int k0 = kt * 32;
    gld_lds16(asD,       aB + k0);
    gld_lds16(asD + 512, aB + 16 * KP + k0);
    gld_lds16(bsD,       bB + k0);
    gld_lds16(bsD + 512, bB + 16 * KP + k0);
    __syncthreads();
    bf16x8 af[4], bfr[4];
#pragma unroll
    for (int i = 0; i < 4; ++i)
      af[i] = *(const bf16x8*)&As[(wm + i * 16 + lr) * 32 + lq * 8];
#pragma unroll
    for (int j = 0; j < 4; ++j)
      bfr[j] = *(const bf16x8*)&Bs[(wn + j * 16 + lr) * 32 + lq * 8];
#pragma unroll
    for (int i = 0; i < 4; ++i)
#pragma unroll
      for (int j = 0; j < 4; ++j)
        acc[i][j] = __builtin_amdgcn_mfma_f32_16x16x32_bf16(af[i], bfr[j], acc[i][j], 0, 0, 0);
    __syncthreads();
  }
  // epilogue: C row m=(lane>>4)*4+r, col n=lane&15
#pragma unroll
  for (int i = 0; i < 4; ++i) {
    int m = bm * 128 + wm + i * 16 + lq * 4;
#pragma unroll
    for (int j = 0; j < 4; ++j) {
      int n = bn * 128 + wn + j * 16 + lr;
      if (n < N) {
        int which = n / EMBED;
        int rem = n - which * EMBED;
        int hh = rem / HS;
        int f = rem - hh * HS;
#pragma unroll
        for (int r = 0; r < 4; ++r) {
          int mm = m + r;
          int bb = mm / CTX;
          int tt = mm - bb * CTX;
          int bh = bb * HEADS + hh;
          __bf16 val = (__bf16)acc[i][j][r];
          if (which == 0)
            Q[((size_t)bh * CTX + tt) * HSQ + f] = val;
          else if (which == 1)
            Ko[((size_t)bh * CTX + tt) * HSQ + f] = val;
          else
            V[((size_t)bh * HSQ + f) * CTX + tt] = val;
        }
      }
    }
  }
}

// ---------------- MFMA flash attention: one block per (b,h) ---------------
// Q,K: [bh][t][80] bf16 ; V: [bh][f][200] bf16 (transposed).
// Out: [B,T,KP] bf16 (pad cols 584..607 zeroed by h==0 blocks).
__global__ __launch_bounds__(256) void attn_kernel(const __bf16* __restrict__ q,
                                                   const __bf16* __restrict__ k,
                                                   const __bf16* __restrict__ v,
                                                   __bf16* __restrict__ o) {
  // LDS: Ks[112][104] + Vt[80][136] + Ps[4][16][136] = 62464 B
  __shared__ __align__(16) __bf16 lds[31232];
  __bf16* Ks = lds;                 // 11648 hw
  __bf16* Vt = lds + 11648;         // 10880 hw
  __bf16* Ps = lds + 22528;         //  8704 hw (4 waves x 2176)

  int tid = threadIdx.x;
  int bh = blockIdx.x;
  int b = bh >> 3, h = bh & 7;
  const __bf16* qg = q + (size_t)bh * (CTX * HSQ);
  const __bf16* kg = k + (size_t)bh * (CTX * HSQ);
  const __bf16* vg = v + (size_t)bh * (HSQ * CTX);

  // zero all LDS once (pad cols MUST be 0.0, not junk: 0*NaN=NaN)
  {
    f32x4* p = (f32x4*)lds;
    for (int i = tid; i < 3904; i += 256) p[i] = f32x4{0.f, 0.f, 0.f, 0.f};
  }
  // zero output pad columns (once per (b,t); h==0 blocks only)
  if (h == 0) {
    bf16x8 z = {};
    for (int i = tid; i < CTX * 3; i += 256) {
      int t = i / 3, seg = i - t * 3;
      *(bf16x8*)&o[((size_t)(b * CTX + t)) * KP + EMBED + seg * 8] = z;
    }
  }
  __syncthreads();

  int wid = tid >> 6, lane = tid & 63;
  int lr = lane & 15, g = lane >> 4;
  __bf16* Pw = Ps + wid * (16 * PSS);
  const int nstr = (wid == 0) ? 4 : 3;   // strips: wid, wid+4, wid+8, (12)
  const float scale = 0.04138029443264672f;  // 584^-0.5

  float ml[4][4], ll[4][4];
  f32x4 ov[4][5];
#pragma unroll
  for (int i = 0; i < 4; ++i)
#pragma unroll
    for (int r = 0; r < 4; ++r) { ml[i][r] = -1e30f; ll[i][r] = 0.f; }
#pragma unroll
  for (int i = 0; i < 4; ++i)
#pragma unroll
    for (int nt = 0; nt < 5; ++nt) ov[i][nt] = f32x4{0.f, 0.f, 0.f, 0.f};

  for (int c = 0; c < 2; ++c) {
    int key0 = c * CH;
    // ---- stage Ks [s][f] from K rows (coalesced: contiguous global) ----
    for (int idx = tid; idx < CH * 10; idx += 256) {
      int s = idx / 10, slot = idx % 10;
      int key = key0 + s;
      if (key < CTX)
        *(bf16x8*)&Ks[s * KSS + slot * 8] =
            *(const bf16x8*)&kg[(size_t)key * HSQ + slot * 8];
    }
    // ---- stage Vt [f][s] from transposed V rows ----
    for (int idx = tid; idx < HSQ * 14; idx += 256) {
      int f = idx / 14, slot = idx % 14;
      int s0 = slot * 8;
      bf16x8 vv;
      if (key0 + s0 + 7 < CTX) {
        vv = *(const bf16x8*)&vg[(size_t)f * CTX + key0 + s0];
      } else {
#pragma unroll
        for (int j = 0; j < 8; ++j)
          vv[j] = (key0 + s0 + j < CTX) ? vg[(size_t)f * CTX + key0 + s0 + j]
                                        : (__bf16)0.f;
      }
      *(bf16x8*)&Vt[f * VTS + s0] = vv;
    }
    __syncthreads();

#pragma unroll
    for (int i = 0; i < 4; ++i) {
      if (i >= nstr) break;
      int strip = wid + 4 * i;
      int row0 = strip * 16;
      // Q A-fragments: A[m=lr][kf=g*8+j + kc*32]
      bf16x8 qf[3];
      qf[0] = *(const bf16x8*)&qg[(size_t)(row0 + lr) * HSQ + g * 8];
      qf[1] = *(const bf16x8*)&qg[(size_t)(row0 + lr) * HSQ + 32 + g * 8];
      if (g < 2)
        qf[2] = *(const bf16x8*)&qg[(size_t)(row0 + lr) * HSQ + 64 + g * 8];
      else
        qf[2] = bf16x8{};
      // ---- S = Q K^T over this chunk ----
      float sc[7][4];
#pragma unroll
      for (int nt = 0; nt < 7; ++nt) {
        f32x4 acc = {};
#pragma unroll
        for (int kc = 0; kc < 3; ++kc) {
          bf16x8 kf = *(const bf16x8*)&Ks[(nt * 16 + lr) * KSS + kc * 32 + g * 8];
          acc = __builtin_amdgcn_mfma_f32_16x16x32_bf16(qf[kc], kf, acc, 0, 0, 0);
        }
        int kcol = key0 + nt * 16 + lr;
#pragma unroll
        for (int r = 0; r < 4; ++r) {
          int qrow = row0 + g * 4 + r;
          sc[nt][r] = (kcol <= qrow && kcol < CTX) ? acc[r] * scale : -1e30f;
        }
      }
      // ---- online softmax (row state; reduce across the 16 lr lanes) ----
      float mc[4];
#pragma unroll
      for (int r = 0; r < 4; ++r) {
        float m = sc[0][r];
#pragma unroll
        for (int nt = 1; nt < 7; ++nt) m = fmaxf(m, sc[nt][r]);
        mc[r] = m;
      }
#pragma unroll
      for (int off = 8; off; off >>= 1)
#pragma unroll
        for (int r = 0; r < 4; ++r)
          mc[r] = fmaxf(mc[r], __shfl_xor(mc[r], off, 64));
      float alpha[4], rs[4];
#pragma unroll
      for (int r = 0; r < 4; ++r) {
        float mnew = fmaxf(ml[i][r], mc[r]);
        alpha[r] = __expf(ml[i][r] - mnew);
        ml[i][r] = mnew;
        float s = 0.f;
#pragma unroll
        for (int nt = 0; nt < 7; ++nt) {
          sc[nt][r] = __expf(sc[nt][r] - mnew);
          s += sc[nt][r];
        }
        rs[r] = s;
      }
#pragma unroll
      for (int off = 8; off; off >>= 1)
#pragma unroll
        for (int r = 0; r < 4; ++r) rs[r] += __shfl_xor(rs[r], off, 64);
#pragma unroll
      for (int r = 0; r < 4; ++r) ll[i][r] = ll[i][r] * alpha[r] + rs[r];
#pragma unroll
      for (int nt = 0; nt < 5; ++nt)
#pragma unroll
        for (int r = 0; r < 4; ++r) ov[i][nt][r] *= alpha[r];
      // ---- P -> per-wave LDS (C-layout -> A-layout round trip) ----
#pragma unroll
      for (int nt = 0; nt < 7; ++nt)
#pragma unroll
        for (int r = 0; r < 4; ++r)
          Pw[(g * 4 + r) * PSS + nt * 16 + lr] = (__bf16)sc[nt][r];
      // ---- O += P V ----
#pragma unroll
      for (int kc = 0; kc < 4; ++kc) {
        bf16x8 pf = *(const bf16x8*)&Pw[lr * PSS + kc * 32 + g * 8];
#pragma unroll
        for (int nt = 0; nt < 5; ++nt) {
          bf16x8 vf = *(const bf16x8*)&Vt[(nt * 16 + lr) * VTS + kc * 32 + g * 8];
          ov[i][nt] = __builtin_amdgcn_mfma_f32_16x16x32_bf16(pf, vf, ov[i][nt], 0, 0, 0);
        }
      }
    }
    __syncthreads();
  }
  // ---- finalize: O / l, store to [B,T,KP] head-concat ----
#pragma unroll
  for (int i = 0; i < 4; ++i) {
    if (i >= nstr) break;
    int strip = wid + 4 * i;
    float inv[4];
#pragma unroll
    for (int r = 0; r < 4; ++r) inv[r] = 1.0f / ll[i][r];
#pragma unroll
    for (int nt = 0; nt < 5; ++nt) {
      int f = nt * 16 + lr;
      if (f < HS) {
#pragma unroll
        for (int r = 0; r < 4; ++r) {
          int t = strip * 16 + g * 4 + r;
          if (t < CTX)
            o[((size_t)(b * CTX + t)) * KP + h * HS + f] =
                (__bf16)(ov[i][nt][r] * inv[r]);
        }
      }
    }
  }
}

// ---------------- output projection GEMM + bias, fp32 out -----------------
__global__ __launch_bounds__(256) void gemm_out(const __bf16* __restrict__ A,
                                                const __bf16* __restrict__ Bm,
                                                const float* __restrict__ bias,
                                                float* __restrict__ C) {
  constexpr int N = EMBED;
  __shared__ __bf16 As[128 * 32];
  __shared__ __bf16 Bs[128 * 32];
  int tid = threadIdx.x;
  int bn = blockIdx.x, bm = blockIdx.y;
  int wid = tid >> 6, lane = tid & 63;
  int wm = (wid & 1) * 64, wn = (wid >> 1) * 64;
  int lr = lane & 15, lq = lane >> 4;
  const __bf16* aB = A  + (size_t)(bm * 128 + wid * 32 + (lane >> 2)) * KP + (lane & 3) * 8;
  const __bf16* bB = Bm + (size_t)(bn * 128 + wid * 32 + (lane >> 2)) * KP + (lane & 3) * 8;
  __bf16* asD = As + wid * 1024;
  __bf16* bsD = Bs + wid * 1024;
  f32x4 acc[4][4] = {};
  for (int kt = 0; kt < 19; ++kt) {
    int k0 = kt * 32;
    gld_lds16(asD,       aB + k0);
    gld_lds16(asD + 512, aB + 16 * KP + k0);
    gld_lds16(bsD,       bB + k0);
    gld_lds16(bsD + 512, bB + 16 * KP + k0);
    __syncthreads();
    bf16x8 af[4], bfr[4];
#pragma unroll
    for (int i = 0; i < 4; ++i)
      af[i] = *(const bf16x8*)&As[(wm + i * 16 + lr) * 32 + lq * 8];
#pragma unroll
    for (int j = 0; j < 4; ++j)
      bfr[j] = *(const bf16x8*)&Bs[(wn + j * 16 + lr) * 32 + lq * 8];
#pragma unroll
    for (int i = 0; i < 4; ++i)
#pragma unroll
      for (int j = 0; j < 4; ++j)
        acc[i][j] = __builtin_amdgcn_mfma_f32_16x16x32_bf16(af[i], bfr[j], acc[i][j], 0, 0, 0);
    __syncthreads();
  }
#pragma unroll
  for (int i = 0; i < 4; ++i) {
    int m = bm * 128 + wm + i * 16 + lq * 4;
#pragma unroll
    for (int j = 0; j < 4; ++j) {
      int n = bn * 128 + wn + j * 16 + lr;
      if (n < N) {
        float bval = bias[n];
#pragma unroll
        for (int r = 0; r < 4; ++r)
          C[(size_t)(m + r) * N + n] = acc[i][j][r] + bval;
      }
    }
  }
}

extern "C" void kernel_launch(void* const* d_in, const int* in_sizes, int n_in,
                              void* d_out, int out_size, void* d_ws, size_t ws_size,
                              hipStream_t stream) {
  const float* x  = (const float*)d_in[0];
  const float* Wq = (const float*)d_in[1];
  const float* Wk = (const float*)d_in[2];
  const float* Wv = (const float*)d_in[3];
  const float* Wo = (const float*)d_in[4];
  const float* bo = (const float*)d_in[5];
  float* out = (float*)d_out;

  // ws layout (bf16 elems), total 130,853,888 elems = 261.7 MB:
  //  xb   [51200*608] = 31,129,600  (reused as ab after gemm_qkv)
  //  wcat [2336*608]  =  1,420,288
  //  qb   [2048*200*80] = 32,768,000
  //  kb   same
  //  vb   same (transposed: [bh][f][t])
  __bf16* xb   = (__bf16*)d_ws;
  __bf16* wcat = xb + 31129600ULL;
  __bf16* qb   = wcat + 1420288ULL;
  __bf16* kb   = qb + 32768000ULL;
  __bf16* vb   = kb + 32768000ULL;
  __bf16* ab   = xb;  // alias: xb dead after gemm_qkv

  cvt_x<<<15200, 256, 0, stream>>>(x, xb);
  pack_w<<<694, 256, 0, stream>>>(Wq, Wk, Wv, Wo, wcat);
  gemm_qkv<<<dim3(14, 400), 256, 0, stream>>>(xb, wcat, qb, kb, vb);
  attn_kernel<<<2048, 256, 0, stream>>>(qb, kb, vb, ab);
  gemm_out<<<dim3(5, 400), 256, 0, stream>>>(ab, wcat + 1752ULL * KP, bo, out);
}